// Round 1
// baseline (451.830 us; speedup 1.0000x reference)
//
#include <hip/hip_runtime.h>

#define N_NODES 50000
#define N_EDGES 1600000
#define D_IN    256
#define HS      32

// ---------------------------------------------------------------------------
// Kernel 1: fused Q/K/V projection.  [N,256] x [256,32] x3, fp32 vector ALU.
// Thread layout: j = t&31 (output col), g = t>>5 (row group of 8 rows).
// Block of 256 threads covers 64 rows. W loads coalesced (128B per 32-lane
// group), X loads are float4 broadcast (same addr across the 32 j-lanes ->
// single transaction).
// ---------------------------------------------------------------------------
__global__ __launch_bounds__(256) void proj_kernel(
    const float* __restrict__ X,  const float* __restrict__ Wq,
    const float* __restrict__ Wk, const float* __restrict__ Wv,
    float* __restrict__ Q, float* __restrict__ K, float* __restrict__ V)
{
    const int t = threadIdx.x;
    const int j = t & 31;   // output column 0..31
    const int g = t >> 5;   // row group 0..7
    const int row0 = blockIdx.x * 64 + g * 8;

    float acc[3][8];
#pragma unroll
    for (int m = 0; m < 3; m++)
#pragma unroll
        for (int i = 0; i < 8; i++) acc[m][i] = 0.f;

    int rows[8];
#pragma unroll
    for (int i = 0; i < 8; i++) {
        int r = row0 + i;
        rows[i] = (r < N_NODES) ? r : (N_NODES - 1);  // clamp; OOB never stored
    }

    for (int k4 = 0; k4 < D_IN / 4; k4++) {
        float4 xv[8];
#pragma unroll
        for (int i = 0; i < 8; i++)
            xv[i] = *(const float4*)(X + (size_t)rows[i] * D_IN + k4 * 4);
#pragma unroll
        for (int kk = 0; kk < 4; kk++) {
            const int k = k4 * 4 + kk;
            const float wq = Wq[k * HS + j];
            const float wk = Wk[k * HS + j];
            const float wv = Wv[k * HS + j];
#pragma unroll
            for (int i = 0; i < 8; i++) {
                const float x = ((const float*)&xv[i])[kk];
                acc[0][i] += x * wq;
                acc[1][i] += x * wk;
                acc[2][i] += x * wv;
            }
        }
    }
#pragma unroll
    for (int i = 0; i < 8; i++) {
        const int r = row0 + i;
        if (r < N_NODES) {
            Q[r * HS + j] = acc[0][i];
            K[r * HS + j] = acc[1][i];
            V[r * HS + j] = acc[2][i];
        }
    }
}

// ---------------------------------------------------------------------------
// Kernel 2: per-edge attention + atomic aggregation.
// One wave handles 2 edges: lanes 0..31 = edge e0 (component j = lane),
// lanes 32..63 = edge e0+1. Softmax shift-invariance lets us skip the
// segment-max pass (scores bounded ~|10| -> exp safe in fp32).
// E is even and grid is exact: no tail guard needed, but keep one anyway.
// ---------------------------------------------------------------------------
__global__ __launch_bounds__(256) void edge_kernel(
    const int* __restrict__ er, const int* __restrict__ ec,
    const float* __restrict__ Q, const float* __restrict__ K,
    const float* __restrict__ V,
    float* __restrict__ num, float* __restrict__ denom)
{
    const int lane = threadIdx.x & 63;
    const int gw   = (blockIdx.x * blockDim.x + threadIdx.x) >> 6;  // wave id
    const int j = lane & 31;
    const int h = lane >> 5;
    const long long e = (long long)gw * 2 + h;
    if (e >= N_EDGES) return;

    const int r = er[e];
    const int c = ec[e];

    const float q = Q[r * HS + j];
    const float k = K[c * HS + j];
    const float v = V[c * HS + j];

    float p = q * k;
    // reduce across the 32 lanes of this half (xor masks <32 stay in-half)
#pragma unroll
    for (int ofs = 1; ofs < 32; ofs <<= 1)
        p += __shfl_xor(p, ofs, 64);

    const float ex = __expf(p * 0.17677669529663687f);  // 1/sqrt(32)

    if (j == 0) atomicAdd(&denom[r], ex);
    atomicAdd(&num[r * HS + j], ex * v);
}

// ---------------------------------------------------------------------------
// Kernel 3: out = denom>0 ? num/denom : 0
// ---------------------------------------------------------------------------
__global__ __launch_bounds__(256) void finalize_kernel(
    float* __restrict__ out, const float* __restrict__ denom)
{
    const int i = blockIdx.x * blockDim.x + threadIdx.x;
    if (i >= N_NODES * HS) return;
    const float d = denom[i >> 5];
    out[i] = (d > 0.f) ? out[i] / d : 0.f;
}

extern "C" void kernel_launch(void* const* d_in, const int* in_sizes, int n_in,
                              void* d_out, int out_size, void* d_ws, size_t ws_size,
                              hipStream_t stream)
{
    const float* X  = (const float*)d_in[0];
    const float* Wq = (const float*)d_in[1];
    const float* Wk = (const float*)d_in[2];
    const float* Wv = (const float*)d_in[3];
    const int*   ei = (const int*)d_in[4];
    const int* er = ei;             // edge_index[0] (query rows)
    const int* ec = ei + N_EDGES;   // edge_index[1] (key/value cols)

    float* out = (float*)d_out;

    // workspace layout: Q | K | V | denom  (19.4 MB)
    float* Q     = (float*)d_ws;
    float* K     = Q + (size_t)N_NODES * HS;
    float* V     = K + (size_t)N_NODES * HS;
    float* denom = V + (size_t)N_NODES * HS;

    hipMemsetAsync(out,   0, (size_t)N_NODES * HS * sizeof(float), stream);
    hipMemsetAsync(denom, 0, (size_t)N_NODES * sizeof(float), stream);

    proj_kernel<<<(N_NODES + 63) / 64, 256, 0, stream>>>(X, Wq, Wk, Wv, Q, K, V);

    // E/2 = 800K waves, 4 waves/block -> exactly 200000 blocks
    edge_kernel<<<(N_EDGES / 2 * 64 + 255) / 256, 256, 0, stream>>>(
        er, ec, Q, K, V, out, denom);

    finalize_kernel<<<(N_NODES * HS + 255) / 256, 256, 0, stream>>>(out, denom);
}